// Round 8
// baseline (112.487 us; speedup 1.0000x reference)
//
#include <hip/hip_runtime.h>
#include <hip/hip_bf16.h>
#include <hip/hip_fp16.h>

#define A_NUM 128
#define U_NUM 8
#define ANT 64
#define D2 64
#define H_DIM 256
#define NUE 1024
#define E_INT 131072

typedef __attribute__((ext_vector_type(8))) short bf16x8_t;
typedef __attribute__((ext_vector_type(4))) float f32x4_t;

// round-to-nearest-even f32 -> bf16
static __device__ inline unsigned short f2bf(float x) {
    unsigned int u = __float_as_uint(x);
    unsigned int r = (u + 0x7fffu + ((u >> 16) & 1u)) >> 16;
    return (unsigned short)r;
}
static __device__ inline unsigned int pack2(float a, float b) {
    return (unsigned int)f2bf(a) | ((unsigned int)f2bf(b) << 16);
}
static __device__ inline bf16x8_t pack8(float4 a, float4 b) {
    union { unsigned int u[4]; bf16x8_t v; } r;
    r.u[0] = pack2(a.x, a.y);
    r.u[1] = pack2(a.z, a.w);
    r.u[2] = pack2(b.x, b.y);
    r.u[3] = pack2(b.z, b.w);
    return r.v;
}
static __device__ inline unsigned int packh2(float a, float b) {
    return (unsigned int)__half_as_ushort(__float2half(a)) |
           ((unsigned int)__half_as_ushort(__float2half(b)) << 16);
}
// opaque register pin: prevents the backend from sinking/rematerializing
static __device__ inline void pin4(uint4& v) {
    asm volatile("" : "+v"(v.x), "+v"(v.y), "+v"(v.z), "+v"(v.w));
}

// ---------------------------------------------------------------------------
// Kernel A: prep. blocks 0..127: Sa[a,h]. blocks 128..135: WpT/W2bT bf16 pack.
// blocks 136..167: f32 transposes W1aT[256][208] (pad), W1bT[128][256].
// ---------------------------------------------------------------------------
__global__ void prep_kernel(const float* __restrict__ pv_re, const float* __restrict__ pv_im,
                            const float* __restrict__ W2a, const float* __restrict__ b2a,
                            const float* __restrict__ W2b,
                            const float* __restrict__ W1a, const float* __restrict__ W1b,
                            float* __restrict__ Sa, unsigned short* __restrict__ WpT,
                            unsigned short* __restrict__ W2bT,
                            float* __restrict__ W1aT, float* __restrict__ W1bT) {
    int bid = blockIdx.x, t = threadIdx.x;
    if (bid < A_NUM) {
        __shared__ float sre[ANT], sim[ANT];
        if (t < ANT) {
            float s = 0.f;
            for (int u = 0; u < U_NUM; ++u) s += pv_re[bid * 512 + u * 64 + t];
            sre[t] = s;
        } else if (t < 2 * ANT) {
            int ant = t - ANT;
            float s = 0.f;
            for (int u = 0; u < U_NUM; ++u) s += pv_im[bid * 512 + u * 64 + ant];
            sim[ant] = s;
        }
        __syncthreads();
        float a0 = 0.f, a1 = 0.f, a2 = 0.f, a3 = 0.f;
        for (int ant = 0; ant < ANT; ant += 2) {
            a0 += sre[ant] * W2a[(64 + ant) * H_DIM + t];
            a1 += sim[ant] * W2a[(192 + ant) * H_DIM + t];
            a2 += sre[ant + 1] * W2a[(64 + ant + 1) * H_DIM + t];
            a3 += sim[ant + 1] * W2a[(192 + ant + 1) * H_DIM + t];
        }
        Sa[bid * H_DIM + t] = b2a[t] + ((a0 + a2) + (a1 + a3));
    } else if (bid < 136) {
        int base = (bid - A_NUM) * 256 + t;
        for (int i = base; i < 32768 + 16384; i += 8 * 256) {
            if (i < 32768) {
                int h = i >> 7, k = i & 127;
                int row = (k < 64) ? k : (k + 64);
                WpT[i] = f2bf(W2a[row * H_DIM + h]);
            } else {
                int i2 = i - 32768;
                int d = i2 >> 8, k2 = i2 & 255;
                W2bT[i2] = f2bf(W2b[k2 * D2 + d]);
            }
        }
    } else {
        for (int i = (bid - 136) * 256 + t; i < 53248 + 32768; i += 32 * 256) {
            if (i < 53248) {
                int k = i >> 8, h = i & 255;
                W1aT[h * 208 + k] = (k < 193) ? W1a[k * 256 + h] : 0.f;
            } else {
                int i2 = i - 53248;
                int k = i2 >> 7, c = i2 & 127;
                W1bT[c * 256 + k] = W1b[k * 128 + c];
            }
        }
    }
}

// ---------------------------------------------------------------------------
// Kernel B: big edge MLP via bf16 MFMA. Block = 16 j x 8 a, 512 thr (8 waves),
// 1024 blocks. Wave w owns layer1 h-eighth + layer2 k-eighth; weights are
// register-pinned (asm) under an exact 4-waves/EU occupancy pin -> 128 VGPR
// budget honestly admits them. No in-loop barriers.
// ---------------------------------------------------------------------------
__global__ void __attribute__((amdgpu_flat_work_group_size(512, 512),
                               amdgpu_waves_per_eu(4, 4)))
mlp2_kernel(const float* __restrict__ plre, const float* __restrict__ plim,
            const float* __restrict__ Sa, const unsigned short* __restrict__ WpT,
            const unsigned short* __restrict__ W2bT, float* __restrict__ partial,
            unsigned short* __restrict__ Pws) {
    // 34816 B: during loop = 8 wave-private Hl[16][40] u16 (2560 B each);
    // after final barrier = red[8][16][68] f32.
    __shared__ __attribute__((aligned(16))) float smraw[8 * 16 * 68];
    int bid = blockIdx.x;
    int ac = bid >> 6, jt = bid & 63;
    int j0 = jt * 16, a0 = ac * 8;
    int t = threadIdx.x, w = t >> 6, l = t & 63, lm = l & 15, lk = l >> 4;
    int h0 = w * 32;

    // ---- register-resident weights (per-wave eighth), asm-pinned ----
    uint4 bfrU[2][4];  // layer1 B: h = h0 + ht*16 + lm, k = kc*32 + lk*8
#pragma unroll
    for (int ht = 0; ht < 2; ++ht)
#pragma unroll
        for (int kc = 0; kc < 4; ++kc) {
            bfrU[ht][kc] = *reinterpret_cast<const uint4*>(
                WpT + (h0 + ht * 16 + lm) * 128 + kc * 32 + lk * 8);
            pin4(bfrU[ht][kc]);
        }
    uint4 b2hU[4];     // layer2 B: d = dt*16 + lm, k = h0 + lk*8 (wave k-eighth)
#pragma unroll
    for (int dt = 0; dt < 4; ++dt) {
        b2hU[dt] = *reinterpret_cast<const uint4*>(
            W2bT + (dt * 16 + lm) * 256 + h0 + lk * 8);
        pin4(b2hU[dt]);
    }

    unsigned short* Hw = reinterpret_cast<unsigned short*>(smraw) + w * (16 * 40);
    f32x4_t acc2[4];
#pragma unroll
    for (int dt = 0; dt < 4; ++dt) acc2[dt] = (f32x4_t){0.f, 0.f, 0.f, 0.f};

    for (int ai = 0; ai < 8; ++ai) {
        int a = a0 + ai;
        const float* rowre = plre + (size_t)(a * 1024 + j0 + lm) * 64;
        const float* rowim = plim + (size_t)(a * 1024 + j0 + lm) * 64;
        float4 r0 = *reinterpret_cast<const float4*>(rowre + lk * 8);
        float4 r1 = *reinterpret_cast<const float4*>(rowre + lk * 8 + 4);
        float4 r2 = *reinterpret_cast<const float4*>(rowre + 32 + lk * 8);
        float4 r3 = *reinterpret_cast<const float4*>(rowre + 32 + lk * 8 + 4);
        float4 i0 = *reinterpret_cast<const float4*>(rowim + lk * 8);
        float4 i1 = *reinterpret_cast<const float4*>(rowim + lk * 8 + 4);
        float4 i2 = *reinterpret_cast<const float4*>(rowim + 32 + lk * 8);
        float4 i3 = *reinterpret_cast<const float4*>(rowim + 32 + lk * 8 + 4);

        // ---- P emit (wave 0 only): P[e][ant] = re^2 + im^2 (fp16) ----
        if (w == 0) {
            unsigned short* pd = Pws + (unsigned)(a * 1024 + j0 + lm) * 64 + lk * 8;
            *reinterpret_cast<uint4*>(pd) = make_uint4(
                packh2(r0.x * r0.x + i0.x * i0.x, r0.y * r0.y + i0.y * i0.y),
                packh2(r0.z * r0.z + i0.z * i0.z, r0.w * r0.w + i0.w * i0.w),
                packh2(r1.x * r1.x + i1.x * i1.x, r1.y * r1.y + i1.y * i1.y),
                packh2(r1.z * r1.z + i1.z * i1.z, r1.w * r1.w + i1.w * i1.w));
            *reinterpret_cast<uint4*>(pd + 32) = make_uint4(
                packh2(r2.x * r2.x + i2.x * i2.x, r2.y * r2.y + i2.y * i2.y),
                packh2(r2.z * r2.z + i2.z * i2.z, r2.w * r2.w + i2.w * i2.w),
                packh2(r3.x * r3.x + i3.x * i3.x, r3.y * r3.y + i3.y * i3.y),
                packh2(r3.z * r3.z + i3.z * i3.z, r3.w * r3.w + i3.w * i3.w));
        }

        // ---- A-fragments ----
        bf16x8_t fa0 = pack8(r0, r1);   // re k 0..31
        bf16x8_t fa1 = pack8(r2, r3);   // re k 32..63
        bf16x8_t fa2 = pack8(i0, i1);   // im k 64..95
        bf16x8_t fa3 = pack8(i2, i3);   // im k 96..127

        // ---- layer 1: 16 j x (wave's 32 h), K=128 ----
        float sa0 = Sa[a * H_DIM + h0 + lm];
        float sa1 = Sa[a * H_DIM + h0 + 16 + lm];
        f32x4_t acc1a = (f32x4_t){sa0, sa0, sa0, sa0};
        f32x4_t acc1b = (f32x4_t){sa1, sa1, sa1, sa1};
        const bf16x8_t* bfr0 = reinterpret_cast<const bf16x8_t*>(&bfrU[0][0]);
        const bf16x8_t* bfr1 = reinterpret_cast<const bf16x8_t*>(&bfrU[1][0]);
        acc1a = __builtin_amdgcn_mfma_f32_16x16x32_bf16(fa0, bfr0[0], acc1a, 0, 0, 0);
        acc1b = __builtin_amdgcn_mfma_f32_16x16x32_bf16(fa0, bfr1[0], acc1b, 0, 0, 0);
        acc1a = __builtin_amdgcn_mfma_f32_16x16x32_bf16(fa1, bfr0[1], acc1a, 0, 0, 0);
        acc1b = __builtin_amdgcn_mfma_f32_16x16x32_bf16(fa1, bfr1[1], acc1b, 0, 0, 0);
        acc1a = __builtin_amdgcn_mfma_f32_16x16x32_bf16(fa2, bfr0[2], acc1a, 0, 0, 0);
        acc1b = __builtin_amdgcn_mfma_f32_16x16x32_bf16(fa2, bfr1[2], acc1b, 0, 0, 0);
        acc1a = __builtin_amdgcn_mfma_f32_16x16x32_bf16(fa3, bfr0[3], acc1a, 0, 0, 0);
        acc1b = __builtin_amdgcn_mfma_f32_16x16x32_bf16(fa3, bfr1[3], acc1b, 0, 0, 0);

        // ---- relu -> bf16 -> wave-private Hl (in-wave DS ordering only) ----
#pragma unroll
        for (int r = 0; r < 4; ++r) {
            int j = lk * 4 + r;
            float va = acc1a[r], vb = acc1b[r];
            Hw[j * 40 + lm] = f2bf(va > 0.f ? va : 0.f);
            Hw[j * 40 + 16 + lm] = f2bf(vb > 0.f ? vb : 0.f);
        }
        // ---- layer 2: wave's k-eighth (32 h) x all 64 d ----
        bf16x8_t a2 = *reinterpret_cast<const bf16x8_t*>(Hw + lm * 40 + lk * 8);
        const bf16x8_t* b2h = reinterpret_cast<const bf16x8_t*>(&b2hU[0]);
#pragma unroll
        for (int dt = 0; dt < 4; ++dt)
            acc2[dt] = __builtin_amdgcn_mfma_f32_16x16x32_bf16(a2, b2h[dt], acc2[dt], 0, 0, 0);
    }

    // ---- cross-wave k-reduce (once per block) ----
    __syncthreads();   // all waves done with their Hl regions
    float* red = smraw;  // [8][16][68]
#pragma unroll
    for (int dt = 0; dt < 4; ++dt)
#pragma unroll
        for (int r = 0; r < 4; ++r)
            red[(w * 16 + lk * 4 + r) * 68 + dt * 16 + lm] = acc2[dt][r];
    __syncthreads();
    for (int i = t; i < 1024; i += 512) {
        int j = i >> 6, d = i & 63;
        float s0 = red[(0 * 16 + j) * 68 + d] + red[(1 * 16 + j) * 68 + d];
        float s1 = red[(2 * 16 + j) * 68 + d] + red[(3 * 16 + j) * 68 + d];
        float s2 = red[(4 * 16 + j) * 68 + d] + red[(5 * 16 + j) * 68 + d];
        float s3 = red[(6 * 16 + j) * 68 + d] + red[(7 * 16 + j) * 68 + d];
        partial[ac * 65536 + (j0 + j) * 64 + d] = (s0 + s1) + (s2 + s3);
    }
}

// ---------------------------------------------------------------------------
// Kernel C: fused d-link MLP + per-AP normalization. One block per AP,
// 512 threads. Also folds the partial-chunk reduction for its 8 ue rows.
// ---------------------------------------------------------------------------
__global__ __launch_bounds__(512) void dlink_norm(
        const float* __restrict__ pv_re, const float* __restrict__ pv_im,
        const float* __restrict__ pldre, const float* __restrict__ pldim,
        const float* __restrict__ partial, const float* __restrict__ b2b,
        const float* __restrict__ W1aT, const float* __restrict__ b1a,
        const float* __restrict__ W1bT, const float* __restrict__ b1b,
        float* __restrict__ Q, float* __restrict__ out) {
    int a = blockIdx.x, t = threadIdx.x, w = t >> 6, l = t & 63;
    __shared__ float pvr[512], pvi[512], pldr[512], pldi[512];
    __shared__ float nrm[8][8];
    __shared__ __attribute__((aligned(16))) float feat[8][212];
    __shared__ __attribute__((aligned(16))) float h1[8][260];
    __shared__ float red2[2][8][128];
    __shared__ __attribute__((aligned(16))) float o1[8][128];
    __shared__ float redn[8];
    __shared__ float SshInv;

    pvr[t] = pv_re[a * 512 + t];
    pvi[t] = pv_im[a * 512 + t];
    pldr[t] = pldre[a * 512 + t];
    pldi[t] = pldim[a * 512 + t];
    {
        float acc = 128.f * b2b[t & 63];
#pragma unroll
        for (int c = 0; c < 16; ++c) acc += partial[c * 65536 + a * 512 + t];
        feat[t >> 6][129 + (t & 63)] = acc;
    }
    if (t < 152) feat[t / 19][193 + t % 19] = 0.f;
    __syncthreads();
    feat[t >> 6][1 + (t & 63)] = pldr[t];
    feat[t >> 6][65 + (t & 63)] = pldi[t];
#pragma unroll
    for (int p = 0; p < 8; ++p) {
        int idx = w * 8 + p;
        int el = idx >> 3, u = idx & 7;
        float pr = pvr[u * 64 + l], pi = pvi[u * 64 + l];
        float qr = pldr[el * 64 + l], qi = pldi[el * 64 + l];
        float ir = pr * qr + pi * qi;
        float ii = pr * qi - pi * qr;
        for (int m = 1; m < 64; m <<= 1) {
            ir += __shfl_xor(ir, m, 64);
            ii += __shfl_xor(ii, m, 64);
        }
        if (l == 0) nrm[el][u] = ir * ir + ii * ii;
    }
    __syncthreads();
    if (t < 8) {
        float s = 0.f;
        for (int u = 0; u < 8; ++u)
            if (u != t) s += nrm[t][u];
        feat[t][0] = s;
    }
    __syncthreads();
    {
        int h = t >> 1, e0 = (t & 1) * 4;
        const float4* wrow = reinterpret_cast<const float4*>(W1aT + h * 208);
        const float4* f0p = reinterpret_cast<const float4*>(&feat[e0 + 0][0]);
        const float4* f1p = reinterpret_cast<const float4*>(&feat[e0 + 1][0]);
        const float4* f2p = reinterpret_cast<const float4*>(&feat[e0 + 2][0]);
        const float4* f3p = reinterpret_cast<const float4*>(&feat[e0 + 3][0]);
        float ac0 = 0.f, ac1 = 0.f, ac2 = 0.f, ac3 = 0.f;
#pragma unroll 4
        for (int kq = 0; kq < 52; ++kq) {
            float4 wv = wrow[kq];
            float4 f0 = f0p[kq], f1 = f1p[kq], f2 = f2p[kq], f3 = f3p[kq];
            ac0 = fmaf(wv.x, f0.x, ac0); ac0 = fmaf(wv.y, f0.y, ac0);
            ac0 = fmaf(wv.z, f0.z, ac0); ac0 = fmaf(wv.w, f0.w, ac0);
            ac1 = fmaf(wv.x, f1.x, ac1); ac1 = fmaf(wv.y, f1.y, ac1);
            ac1 = fmaf(wv.z, f1.z, ac1); ac1 = fmaf(wv.w, f1.w, ac1);
            ac2 = fmaf(wv.x, f2.x, ac2); ac2 = fmaf(wv.y, f2.y, ac2);
            ac2 = fmaf(wv.z, f2.z, ac2); ac2 = fmaf(wv.w, f2.w, ac2);
            ac3 = fmaf(wv.x, f3.x, ac3); ac3 = fmaf(wv.y, f3.y, ac3);
            ac3 = fmaf(wv.z, f3.z, ac3); ac3 = fmaf(wv.w, f3.w, ac3);
        }
        float bb = b1a[h];
        float s0 = bb + ac0, s1 = bb + ac1, s2 = bb + ac2, s3 = bb + ac3;
        h1[e0 + 0][h] = s0 > 0.f ? s0 : 0.f;
        h1[e0 + 1][h] = s1 > 0.f ? s1 : 0.f;
        h1[e0 + 2][h] = s2 > 0.f ? s2 : 0.f;
        h1[e0 + 3][h] = s3 > 0.f ? s3 : 0.f;
    }
    __syncthreads();
    {
        int e0 = (t & 1) * 4, c = (t >> 1) & 127, kh = t >> 8;
        const float4* wrow = reinterpret_cast<const float4*>(W1bT + c * 256 + kh * 128);
        const float4* g0 = reinterpret_cast<const float4*>(&h1[e0 + 0][kh * 128]);
        const float4* g1 = reinterpret_cast<const float4*>(&h1[e0 + 1][kh * 128]);
        const float4* g2 = reinterpret_cast<const float4*>(&h1[e0 + 2][kh * 128]);
        const float4* g3 = reinterpret_cast<const float4*>(&h1[e0 + 3][kh * 128]);
        float ac0 = 0.f, ac1 = 0.f, ac2 = 0.f, ac3 = 0.f;
#pragma unroll 4
        for (int kq = 0; kq < 32; ++kq) {
            float4 wv = wrow[kq];
            float4 f0 = g0[kq], f1 = g1[kq], f2 = g2[kq], f3 = g3[kq];
            ac0 = fmaf(wv.x, f0.x, ac0); ac0 = fmaf(wv.y, f0.y, ac0);
            ac0 = fmaf(wv.z, f0.z, ac0); ac0 = fmaf(wv.w, f0.w, ac0);
            ac1 = fmaf(wv.x, f1.x, ac1); ac1 = fmaf(wv.y, f1.y, ac1);
            ac1 = fmaf(wv.z, f1.z, ac1); ac1 = fmaf(wv.w, f1.w, ac1);
            ac2 = fmaf(wv.x, f2.x, ac2); ac2 = fmaf(wv.y, f2.y, ac2);
            ac2 = fmaf(wv.z, f2.z, ac2); ac2 = fmaf(wv.w, f2.w, ac2);
            ac3 = fmaf(wv.x, f3.x, ac3); ac3 = fmaf(wv.y, f3.y, ac3);
            ac3 = fmaf(wv.z, f3.z, ac3); ac3 = fmaf(wv.w, f3.w, ac3);
        }
        red2[kh][e0 + 0][c] = ac0;
        red2[kh][e0 + 1][c] = ac1;
        red2[kh][e0 + 2][c] = ac2;
        red2[kh][e0 + 3][c] = ac3;
    }
    __syncthreads();
    {
        int i0 = t, i1 = t + 512;
        o1[i0 >> 7][i0 & 127] = b1b[i0 & 127] + red2[0][i0 >> 7][i0 & 127] + red2[1][i0 >> 7][i0 & 127];
        o1[i1 >> 7][i1 & 127] = b1b[i1 & 127] + red2[0][i1 >> 7][i1 & 127] + red2[1][i1 >> 7][i1 & 127];
    }
    __syncthreads();
    {
        int el = t >> 6, ant = t & 63;
        float re = o1[el][ant], im = o1[el][64 + ant];
        float v = sqrtf(re * re + im * im);
        for (int m = 1; m < 64; m <<= 1) v += __shfl_xor(v, m, 64);
        if (l == 0) redn[w] = v;
    }
    __syncthreads();
    if (t == 0) {
        float S = redn[0] + redn[1] + redn[2] + redn[3] +
                  redn[4] + redn[5] + redn[6] + redn[7];
        SshInv = 1.f / S;
    }
    __syncthreads();
    {
        float inv = SshInv;
        int el = t >> 6, ant = t & 63;
        out[a * 512 + t] = o1[el][ant] * inv;
        out[65536 + a * 512 + t] = o1[el][64 + ant] * inv;
        if (t < 64) {
            float sr = 0.f, si = 0.f;
#pragma unroll
            for (int u = 0; u < 8; ++u) {
                sr += o1[u][t];
                si += o1[u][64 + t];
            }
            sr *= inv;
            si *= inv;
            Q[a * 64 + t] = sr * sr + si * si;
        }
    }
}

// ---------------------------------------------------------------------------
// Kernel D: final aggregate from fp16 P (16.8 MB). One wave per j.
// ---------------------------------------------------------------------------
__global__ __launch_bounds__(256) void final_agg(const unsigned short* __restrict__ Pws,
                                                 const float* __restrict__ Qv,
                                                 float* __restrict__ out) {
    int bid = blockIdx.x, t = threadIdx.x, w = t >> 6, l = t & 63;
    __shared__ __attribute__((aligned(16))) float Qc[128][68];
    for (int i = t; i < 8192; i += 256) Qc[i >> 6][i & 63] = Qv[i];
    __syncthreads();
    int j = bid * 4 + w;
    int as = l >> 3, og = l & 7;
    float acc = 0.f;
#pragma unroll 4
    for (int ab = 0; ab < 16; ++ab) {
        int aa = ab * 8 + as;
        uint4 pv4 = *reinterpret_cast<const uint4*>(&Pws[(unsigned)(aa * 1024 + j) * 64 + og * 8]);
        float4 q0 = *reinterpret_cast<const float4*>(&Qc[aa][og * 8]);
        float4 q1 = *reinterpret_cast<const float4*>(&Qc[aa][og * 8 + 4]);
        const unsigned short* hp = (const unsigned short*)&pv4;
        acc += __half2float(__ushort_as_half(hp[0])) * q0.x;
        acc += __half2float(__ushort_as_half(hp[1])) * q0.y;
        acc += __half2float(__ushort_as_half(hp[2])) * q0.z;
        acc += __half2float(__ushort_as_half(hp[3])) * q0.w;
        acc += __half2float(__ushort_as_half(hp[4])) * q1.x;
        acc += __half2float(__ushort_as_half(hp[5])) * q1.y;
        acc += __half2float(__ushort_as_half(hp[6])) * q1.z;
        acc += __half2float(__ushort_as_half(hp[7])) * q1.w;
    }
    for (int m = 1; m < 64; m <<= 1) acc += __shfl_xor(acc, m, 64);
    if (l == 0) out[131072 + j] = acc;
}

extern "C" void kernel_launch(void* const* d_in, const int* in_sizes, int n_in,
                              void* d_out, int out_size, void* d_ws, size_t ws_size,
                              hipStream_t stream) {
    const float* plre = (const float*)d_in[0];
    const float* plim = (const float*)d_in[1];
    const float* pldre = (const float*)d_in[2];
    const float* pldim = (const float*)d_in[3];
    const float* pvre = (const float*)d_in[4];
    const float* pvim = (const float*)d_in[5];
    const float* W2a = (const float*)d_in[6];
    const float* b2a = (const float*)d_in[7];
    const float* W2b = (const float*)d_in[8];
    const float* b2b = (const float*)d_in[9];
    const float* W1a = (const float*)d_in[10];
    const float* b1a = (const float*)d_in[11];
    const float* W1b = (const float*)d_in[12];
    const float* b1b = (const float*)d_in[13];

    char* ws = (char*)d_ws;
    float* Sa = (float*)(ws);                               // 131072 B
    unsigned short* WpT = (unsigned short*)(ws + 131072);   // 65536 B
    unsigned short* W2bT = (unsigned short*)(ws + 196608);  // 32768 B
    float* Q = (float*)(ws + 229376);                       // 32768 B
    float* partial = (float*)(ws + 262144);                 // 4194304 B
    unsigned short* Pws = (unsigned short*)(ws + 4456448);  // 16777216 B
    float* W1aT = (float*)(ws + 21233664);                  // 212992 B
    float* W1bT = (float*)(ws + 21446656);                  // 131072 B
    float* out = (float*)d_out;

    prep_kernel<<<168, 256, 0, stream>>>(pvre, pvim, W2a, b2a, W2b, W1a, W1b,
                                         Sa, WpT, W2bT, W1aT, W1bT);
    mlp2_kernel<<<1024, 512, 0, stream>>>(plre, plim, Sa, WpT, W2bT, partial, Pws);
    dlink_norm<<<128, 512, 0, stream>>>(pvre, pvim, pldre, pldim, partial, b2b,
                                        W1aT, b1a, W1bT, b1b, Q, out);
    final_agg<<<256, 256, 0, stream>>>(Pws, Q, out);
}

// Round 9
// 76.416 us; speedup vs baseline: 1.4720x; 1.4720x over previous
//
#include <hip/hip_runtime.h>
#include <hip/hip_bf16.h>
#include <hip/hip_fp16.h>

#define A_NUM 128
#define U_NUM 8
#define ANT 64
#define D2 64
#define H_DIM 256
#define NUE 1024
#define E_INT 131072

typedef __attribute__((ext_vector_type(8))) short bf16x8_t;
typedef __attribute__((ext_vector_type(4))) float f32x4_t;

// round-to-nearest-even f32 -> bf16
static __device__ inline unsigned short f2bf(float x) {
    unsigned int u = __float_as_uint(x);
    unsigned int r = (u + 0x7fffu + ((u >> 16) & 1u)) >> 16;
    return (unsigned short)r;
}
static __device__ inline unsigned int pack2(float a, float b) {
    return (unsigned int)f2bf(a) | ((unsigned int)f2bf(b) << 16);
}
static __device__ inline unsigned int packh2(float a, float b) {
    return (unsigned int)__half_as_ushort(__float2half(a)) |
           ((unsigned int)__half_as_ushort(__float2half(b)) << 16);
}

// ---------------------------------------------------------------------------
// Kernel A: prep. blocks 0..127: Sa[a,h]. blocks 128..135: fragment-order
// bf16 weight packs WpF/W2bF for the MFMA kernel. blocks 136..167: f32
// transposes W1aT[256][208] (pad), W1bT[128][256].
//
// WpF flat = hh*16384 + w*4096 + ht*2048 + kc*512 + l*8 + i
//   -> element Wp[h][k], h = hh*128+w*32+ht*16+(l&15), k = kc*32+(l>>4)*8+i,
//      Wp[h][k] = W2a[k<64 ? k : k+64][h]
// W2bF flat = hh*8192 + w*2048 + dt*512 + l*8 + i
//   -> W2b[k][d], d = dt*16+(l&15), k = hh*128+w*32+(l>>4)*8+i
// ---------------------------------------------------------------------------
__global__ void prep_kernel(const float* __restrict__ pv_re, const float* __restrict__ pv_im,
                            const float* __restrict__ W2a, const float* __restrict__ b2a,
                            const float* __restrict__ W2b,
                            const float* __restrict__ W1a, const float* __restrict__ W1b,
                            float* __restrict__ Sa, unsigned short* __restrict__ WpF,
                            unsigned short* __restrict__ W2bF,
                            float* __restrict__ W1aT, float* __restrict__ W1bT) {
    int bid = blockIdx.x, t = threadIdx.x;
    if (bid < A_NUM) {
        __shared__ float sre[ANT], sim[ANT];
        if (t < ANT) {
            float s = 0.f;
            for (int u = 0; u < U_NUM; ++u) s += pv_re[bid * 512 + u * 64 + t];
            sre[t] = s;
        } else if (t < 2 * ANT) {
            int ant = t - ANT;
            float s = 0.f;
            for (int u = 0; u < U_NUM; ++u) s += pv_im[bid * 512 + u * 64 + ant];
            sim[ant] = s;
        }
        __syncthreads();
        float a0 = 0.f, a1 = 0.f, a2 = 0.f, a3 = 0.f;
        for (int ant = 0; ant < ANT; ant += 2) {
            a0 += sre[ant] * W2a[(64 + ant) * H_DIM + t];
            a1 += sim[ant] * W2a[(192 + ant) * H_DIM + t];
            a2 += sre[ant + 1] * W2a[(64 + ant + 1) * H_DIM + t];
            a3 += sim[ant + 1] * W2a[(192 + ant + 1) * H_DIM + t];
        }
        Sa[bid * H_DIM + t] = b2a[t] + ((a0 + a2) + (a1 + a3));
    } else if (bid < 136) {
        int base = (bid - A_NUM) * 256 + t;
        for (int f = base; f < 32768 + 16384; f += 8 * 256) {
            if (f < 32768) {  // WpF
                int i = f & 7, lml = (f >> 3) & 15, lkl = (f >> 7) & 3;
                int kc = (f >> 9) & 3, ht = (f >> 11) & 1, w = (f >> 12) & 3, hh = (f >> 14) & 1;
                int h = hh * 128 + w * 32 + ht * 16 + lml;
                int k = kc * 32 + lkl * 8 + i;
                int row = (k < 64) ? k : (k + 64);
                WpF[f] = f2bf(W2a[row * H_DIM + h]);
            } else {          // W2bF
                int f2 = f - 32768;
                int i = f2 & 7, lml = (f2 >> 3) & 15, lkl = (f2 >> 7) & 3;
                int dt = (f2 >> 9) & 3, w = (f2 >> 11) & 3, hh = (f2 >> 13) & 1;
                int d = dt * 16 + lml;
                int k = hh * 128 + w * 32 + lkl * 8 + i;
                W2bF[f2] = f2bf(W2b[k * D2 + d]);
            }
        }
    } else {
        for (int i = (bid - 136) * 256 + t; i < 53248 + 32768; i += 32 * 256) {
            if (i < 53248) {
                int k = i >> 8, h = i & 255;
                W1aT[h * 208 + k] = (k < 193) ? W1a[k * 256 + h] : 0.f;
            } else {
                int i2 = i - 53248;
                int k = i2 >> 7, c = i2 & 127;
                W1bT[c * 256 + k] = W1b[k * 128 + c];
            }
        }
    }
}

// ---------------------------------------------------------------------------
// Kernel B: big edge MLP via bf16 MFMA, LDS-resident weights, h-split blocks.
// Grid 1024 = 32 jt x 2 hh x 16 ac; 256 thr (4 waves); j-tile 32; 8 a-iters.
// Wave w: layer1 h-slice [hh*128+w*32, +32); layer2 same slice as k-split.
// All loop operands are LDS; F double-buffered; 1 barrier/iter.
// ---------------------------------------------------------------------------
__global__ __launch_bounds__(256) void mlp2_kernel(
        const float* __restrict__ plre, const float* __restrict__ plim,
        const float* __restrict__ Sa, const unsigned short* __restrict__ WpF,
        const unsigned short* __restrict__ W2bF, float* __restrict__ partial,
        unsigned short* __restrict__ Pws) {
    __shared__ __attribute__((aligned(16))) unsigned short Wl[16384];      // 32KB frag-order
    __shared__ __attribute__((aligned(16))) unsigned short W2l[8192];      // 16KB frag-order
    __shared__ __attribute__((aligned(16))) unsigned short F2[2][4352];    // 2x[32][136]
    __shared__ __attribute__((aligned(16))) unsigned short Hw_all[4][1280];// wave [32][40]
    int bid = blockIdx.x;
    int ac = bid >> 6, hh = (bid >> 5) & 1, jt = bid & 31;
    int j0 = jt * 32, a0 = ac * 8;
    int t = threadIdx.x, w = t >> 6, l = t & 63, lm = l & 15, lk = l >> 4;

    // ---- stage this hh-half's weights into LDS (once) ----
    {
        const uint4* srcW = reinterpret_cast<const uint4*>(WpF + hh * 16384);
        const uint4* srcW2 = reinterpret_cast<const uint4*>(W2bF + hh * 8192);
        uint4* dW = reinterpret_cast<uint4*>(Wl);
        uint4* dW2 = reinterpret_cast<uint4*>(W2l);
        for (int q = t; q < 3072; q += 256) {
            if (q < 2048) dW[q] = srcW[q];
            else dW2[q - 2048] = srcW2[q - 2048];
        }
    }

    // ---- staging identity: thread t -> (row er, 16-col segment sg) ----
    int er = t >> 3, sg = t & 7;
    const float* sb = (sg < 4) ? plre : plim;
    int soff = (j0 + er) * 64 + (sg & 3) * 16;
    int fw = er * 136 + sg * 16;

    unsigned short* Hw = Hw_all[w];
    f32x4_t acc2[4][2];  // [dt][jg]
#pragma unroll
    for (int dt = 0; dt < 4; ++dt)
#pragma unroll
        for (int jg = 0; jg < 2; ++jg) acc2[dt][jg] = (f32x4_t){0.f, 0.f, 0.f, 0.f};

    float4 s0, s1, s2, s3;
    {   // stage a0 directly into F2[0]
        const float* p = sb + (size_t)a0 * 65536 + soff;
        s0 = *reinterpret_cast<const float4*>(p);
        s1 = *reinterpret_cast<const float4*>(p + 4);
        s2 = *reinterpret_cast<const float4*>(p + 8);
        s3 = *reinterpret_cast<const float4*>(p + 12);
        *reinterpret_cast<uint4*>(&F2[0][fw]) =
            make_uint4(pack2(s0.x, s0.y), pack2(s0.z, s0.w),
                       pack2(s1.x, s1.y), pack2(s1.z, s1.w));
        *reinterpret_cast<uint4*>(&F2[0][fw + 8]) =
            make_uint4(pack2(s2.x, s2.y), pack2(s2.z, s2.w),
                       pack2(s3.x, s3.y), pack2(s3.z, s3.w));
    }
    {   // prefetch a0+1
        const float* p = sb + (size_t)(a0 + 1) * 65536 + soff;
        s0 = *reinterpret_cast<const float4*>(p);
        s1 = *reinterpret_cast<const float4*>(p + 4);
        s2 = *reinterpret_cast<const float4*>(p + 8);
        s3 = *reinterpret_cast<const float4*>(p + 12);
    }
    __syncthreads();  // weights + F2[0] visible

    int cur = 0;
    for (int ai = 0; ai < 8; ++ai) {
        int a = a0 + ai;
        const unsigned short* Fc = F2[cur];

        // ---- P emit (hh==0 blocks only): P[e][ant] = re^2+im^2 (fp16) ----
        if (hh == 0) {
            uint4 rr = *reinterpret_cast<const uint4*>(Fc + er * 136 + sg * 8);
            uint4 ri = *reinterpret_cast<const uint4*>(Fc + er * 136 + 64 + sg * 8);
            const unsigned short* pr = (const unsigned short*)&rr;
            const unsigned short* pi = (const unsigned short*)&ri;
            unsigned int pk[4];
#pragma unroll
            for (int i = 0; i < 4; ++i) {
                float re0 = __uint_as_float(((unsigned int)pr[2 * i]) << 16);
                float im0 = __uint_as_float(((unsigned int)pi[2 * i]) << 16);
                float re1 = __uint_as_float(((unsigned int)pr[2 * i + 1]) << 16);
                float im1 = __uint_as_float(((unsigned int)pi[2 * i + 1]) << 16);
                pk[i] = packh2(re0 * re0 + im0 * im0, re1 * re1 + im1 * im1);
            }
            *reinterpret_cast<uint4*>(&Pws[(unsigned)(a * 1024 + j0 + er) * 64 + sg * 8]) =
                make_uint4(pk[0], pk[1], pk[2], pk[3]);
        }

        // ---- layer 1: 32 j x wave's 32 h, K=128 ----
        float sa0 = Sa[a * H_DIM + hh * 128 + w * 32 + lm];
        float sa1 = Sa[a * H_DIM + hh * 128 + w * 32 + 16 + lm];
        f32x4_t acc1[2][2];  // [jg][ht]
        acc1[0][0] = (f32x4_t){sa0, sa0, sa0, sa0};
        acc1[1][0] = acc1[0][0];
        acc1[0][1] = (f32x4_t){sa1, sa1, sa1, sa1};
        acc1[1][1] = acc1[0][1];
#pragma unroll
        for (int kc = 0; kc < 4; ++kc) {
            bf16x8_t b0 = *reinterpret_cast<const bf16x8_t*>(Wl + ((w * 2 + 0) * 4 + kc) * 512 + l * 8);
            bf16x8_t b1 = *reinterpret_cast<const bf16x8_t*>(Wl + ((w * 2 + 1) * 4 + kc) * 512 + l * 8);
            bf16x8_t aA = *reinterpret_cast<const bf16x8_t*>(Fc + lm * 136 + kc * 32 + lk * 8);
            bf16x8_t aB = *reinterpret_cast<const bf16x8_t*>(Fc + (16 + lm) * 136 + kc * 32 + lk * 8);
            acc1[0][0] = __builtin_amdgcn_mfma_f32_16x16x32_bf16(aA, b0, acc1[0][0], 0, 0, 0);
            acc1[0][1] = __builtin_amdgcn_mfma_f32_16x16x32_bf16(aA, b1, acc1[0][1], 0, 0, 0);
            acc1[1][0] = __builtin_amdgcn_mfma_f32_16x16x32_bf16(aB, b0, acc1[1][0], 0, 0, 0);
            acc1[1][1] = __builtin_amdgcn_mfma_f32_16x16x32_bf16(aB, b1, acc1[1][1], 0, 0, 0);
        }
        // ---- relu -> bf16 -> wave-private Hw [32 j][40] ----
#pragma unroll
        for (int jg = 0; jg < 2; ++jg)
#pragma unroll
            for (int ht = 0; ht < 2; ++ht)
#pragma unroll
                for (int r = 0; r < 4; ++r) {
                    float v = acc1[jg][ht][r];
                    Hw[(jg * 16 + lk * 4 + r) * 40 + ht * 16 + lm] = f2bf(v > 0.f ? v : 0.f);
                }
        // ---- layer 2: wave's 32-k slice x 64 d (in-wave DS ordering) ----
        {
            bf16x8_t a20 = *reinterpret_cast<const bf16x8_t*>(Hw + lm * 40 + lk * 8);
            bf16x8_t a21 = *reinterpret_cast<const bf16x8_t*>(Hw + (16 + lm) * 40 + lk * 8);
#pragma unroll
            for (int dt = 0; dt < 4; ++dt) {
                bf16x8_t b2 = *reinterpret_cast<const bf16x8_t*>(W2l + (w * 4 + dt) * 512 + l * 8);
                acc2[dt][0] = __builtin_amdgcn_mfma_f32_16x16x32_bf16(a20, b2, acc2[dt][0], 0, 0, 0);
                acc2[dt][1] = __builtin_amdgcn_mfma_f32_16x16x32_bf16(a21, b2, acc2[dt][1], 0, 0, 0);
            }
        }
        // ---- stage next tile into other buffer; single barrier ----
        if (ai < 7) {
            *reinterpret_cast<uint4*>(&F2[cur ^ 1][fw]) =
                make_uint4(pack2(s0.x, s0.y), pack2(s0.z, s0.w),
                           pack2(s1.x, s1.y), pack2(s1.z, s1.w));
            *reinterpret_cast<uint4*>(&F2[cur ^ 1][fw + 8]) =
                make_uint4(pack2(s2.x, s2.y), pack2(s2.z, s2.w),
                           pack2(s3.x, s3.y), pack2(s3.z, s3.w));
            if (ai < 6) {
                const float* p = sb + (size_t)(a0 + ai + 2) * 65536 + soff;
                s0 = *reinterpret_cast<const float4*>(p);
                s1 = *reinterpret_cast<const float4*>(p + 4);
                s2 = *reinterpret_cast<const float4*>(p + 8);
                s3 = *reinterpret_cast<const float4*>(p + 12);
            }
            __syncthreads();
            cur ^= 1;
        }
    }

    // ---- cross-wave k-reduce; red overlays dead Wl (32KB) ----
    __syncthreads();
    float* red = reinterpret_cast<float*>(Wl);  // [4 w][32 j][64 d]
#pragma unroll
    for (int dt = 0; dt < 4; ++dt)
#pragma unroll
        for (int jg = 0; jg < 2; ++jg)
#pragma unroll
            for (int r = 0; r < 4; ++r)
                red[(w * 32 + jg * 16 + lk * 4 + r) * 64 + dt * 16 + lm] = acc2[dt][jg][r];
    __syncthreads();
    for (int idx = t; idx < 2048; idx += 256) {
        int j = idx >> 6, d = idx & 63;
        float s = (red[(0 * 32 + j) * 64 + d] + red[(1 * 32 + j) * 64 + d]) +
                  (red[(2 * 32 + j) * 64 + d] + red[(3 * 32 + j) * 64 + d]);
        partial[(hh * 16 + ac) * 65536 + (j0 + j) * 64 + d] = s;
    }
}

// ---------------------------------------------------------------------------
// Kernel C: fused d-link MLP + per-AP normalization. One block per AP,
// 512 threads. Folds the 32-chunk partial reduction for its 8 ue rows.
// ---------------------------------------------------------------------------
__global__ __launch_bounds__(512) void dlink_norm(
        const float* __restrict__ pv_re, const float* __restrict__ pv_im,
        const float* __restrict__ pldre, const float* __restrict__ pldim,
        const float* __restrict__ partial, const float* __restrict__ b2b,
        const float* __restrict__ W1aT, const float* __restrict__ b1a,
        const float* __restrict__ W1bT, const float* __restrict__ b1b,
        float* __restrict__ Q, float* __restrict__ out) {
    int a = blockIdx.x, t = threadIdx.x, w = t >> 6, l = t & 63;
    __shared__ float pvr[512], pvi[512], pldr[512], pldi[512];
    __shared__ float nrm[8][8];
    __shared__ __attribute__((aligned(16))) float feat[8][212];
    __shared__ __attribute__((aligned(16))) float h1[8][260];
    __shared__ float red2[2][8][128];
    __shared__ __attribute__((aligned(16))) float o1[8][128];
    __shared__ float redn[8];
    __shared__ float SshInv;

    pvr[t] = pv_re[a * 512 + t];
    pvi[t] = pv_im[a * 512 + t];
    pldr[t] = pldre[a * 512 + t];
    pldi[t] = pldim[a * 512 + t];
    {
        float acc = 128.f * b2b[t & 63];
#pragma unroll
        for (int c = 0; c < 32; ++c) acc += partial[c * 65536 + a * 512 + t];
        feat[t >> 6][129 + (t & 63)] = acc;
    }
    if (t < 152) feat[t / 19][193 + t % 19] = 0.f;
    __syncthreads();
    feat[t >> 6][1 + (t & 63)] = pldr[t];
    feat[t >> 6][65 + (t & 63)] = pldi[t];
#pragma unroll
    for (int p = 0; p < 8; ++p) {
        int idx = w * 8 + p;
        int el = idx >> 3, u = idx & 7;
        float pr = pvr[u * 64 + l], pi = pvi[u * 64 + l];
        float qr = pldr[el * 64 + l], qi = pldi[el * 64 + l];
        float ir = pr * qr + pi * qi;
        float ii = pr * qi - pi * qr;
        for (int m = 1; m < 64; m <<= 1) {
            ir += __shfl_xor(ir, m, 64);
            ii += __shfl_xor(ii, m, 64);
        }
        if (l == 0) nrm[el][u] = ir * ir + ii * ii;
    }
    __syncthreads();
    if (t < 8) {
        float s = 0.f;
        for (int u = 0; u < 8; ++u)
            if (u != t) s += nrm[t][u];
        feat[t][0] = s;
    }
    __syncthreads();
    {
        int h = t >> 1, e0 = (t & 1) * 4;
        const float4* wrow = reinterpret_cast<const float4*>(W1aT + h * 208);
        const float4* f0p = reinterpret_cast<const float4*>(&feat[e0 + 0][0]);
        const float4* f1p = reinterpret_cast<const float4*>(&feat[e0 + 1][0]);
        const float4* f2p = reinterpret_cast<const float4*>(&feat[e0 + 2][0]);
        const float4* f3p = reinterpret_cast<const float4*>(&feat[e0 + 3][0]);
        float ac0 = 0.f, ac1 = 0.f, ac2 = 0.f, ac3 = 0.f;
#pragma unroll 4
        for (int kq = 0; kq < 52; ++kq) {
            float4 wv = wrow[kq];
            float4 f0 = f0p[kq], f1 = f1p[kq], f2 = f2p[kq], f3 = f3p[kq];
            ac0 = fmaf(wv.x, f0.x, ac0); ac0 = fmaf(wv.y, f0.y, ac0);
            ac0 = fmaf(wv.z, f0.z, ac0); ac0 = fmaf(wv.w, f0.w, ac0);
            ac1 = fmaf(wv.x, f1.x, ac1); ac1 = fmaf(wv.y, f1.y, ac1);
            ac1 = fmaf(wv.z, f1.z, ac1); ac1 = fmaf(wv.w, f1.w, ac1);
            ac2 = fmaf(wv.x, f2.x, ac2); ac2 = fmaf(wv.y, f2.y, ac2);
            ac2 = fmaf(wv.z, f2.z, ac2); ac2 = fmaf(wv.w, f2.w, ac2);
            ac3 = fmaf(wv.x, f3.x, ac3); ac3 = fmaf(wv.y, f3.y, ac3);
            ac3 = fmaf(wv.z, f3.z, ac3); ac3 = fmaf(wv.w, f3.w, ac3);
        }
        float bb = b1a[h];
        float s0 = bb + ac0, s1 = bb + ac1, s2 = bb + ac2, s3 = bb + ac3;
        h1[e0 + 0][h] = s0 > 0.f ? s0 : 0.f;
        h1[e0 + 1][h] = s1 > 0.f ? s1 : 0.f;
        h1[e0 + 2][h] = s2 > 0.f ? s2 : 0.f;
        h1[e0 + 3][h] = s3 > 0.f ? s3 : 0.f;
    }
    __syncthreads();
    {
        int e0 = (t & 1) * 4, c = (t >> 1) & 127, kh = t >> 8;
        const float4* wrow = reinterpret_cast<const float4*>(W1bT + c * 256 + kh * 128);
        const float4* g0 = reinterpret_cast<const float4*>(&h1[e0 + 0][kh * 128]);
        const float4* g1 = reinterpret_cast<const float4*>(&h1[e0 + 1][kh * 128]);
        const float4* g2 = reinterpret_cast<const float4*>(&h1[e0 + 2][kh * 128]);
        const float4* g3 = reinterpret_cast<const float4*>(&h1[e0 + 3][kh * 128]);
        float ac0 = 0.f, ac1 = 0.f, ac2 = 0.f, ac3 = 0.f;
#pragma unroll 4
        for (int kq = 0; kq < 32; ++kq) {
            float4 wv = wrow[kq];
            float4 f0 = g0[kq], f1 = g1[kq], f2 = g2[kq], f3 = g3[kq];
            ac0 = fmaf(wv.x, f0.x, ac0); ac0 = fmaf(wv.y, f0.y, ac0);
            ac0 = fmaf(wv.z, f0.z, ac0); ac0 = fmaf(wv.w, f0.w, ac0);
            ac1 = fmaf(wv.x, f1.x, ac1); ac1 = fmaf(wv.y, f1.y, ac1);
            ac1 = fmaf(wv.z, f1.z, ac1); ac1 = fmaf(wv.w, f1.w, ac1);
            ac2 = fmaf(wv.x, f2.x, ac2); ac2 = fmaf(wv.y, f2.y, ac2);
            ac2 = fmaf(wv.z, f2.z, ac2); ac2 = fmaf(wv.w, f2.w, ac2);
            ac3 = fmaf(wv.x, f3.x, ac3); ac3 = fmaf(wv.y, f3.y, ac3);
            ac3 = fmaf(wv.z, f3.z, ac3); ac3 = fmaf(wv.w, f3.w, ac3);
        }
        red2[kh][e0 + 0][c] = ac0;
        red2[kh][e0 + 1][c] = ac1;
        red2[kh][e0 + 2][c] = ac2;
        red2[kh][e0 + 3][c] = ac3;
    }
    __syncthreads();
    {
        int i0 = t, i1 = t + 512;
        o1[i0 >> 7][i0 & 127] = b1b[i0 & 127] + red2[0][i0 >> 7][i0 & 127] + red2[1][i0 >> 7][i0 & 127];
        o1[i1 >> 7][i1 & 127] = b1b[i1 & 127] + red2[0][i1 >> 7][i1 & 127] + red2[1][i1 >> 7][i1 & 127];
    }
    __syncthreads();
    {
        int el = t >> 6, ant = t & 63;
        float re = o1[el][ant], im = o1[el][64 + ant];
        float v = sqrtf(re * re + im * im);
        for (int m = 1; m < 64; m <<= 1) v += __shfl_xor(v, m, 64);
        if (l == 0) redn[w] = v;
    }
    __syncthreads();
    if (t == 0) {
        float S = redn[0] + redn[1] + redn[2] + redn[3] +
                  redn[4] + redn[5] + redn[6] + redn[7];
        SshInv = 1.f / S;
    }
    __syncthreads();
    {
        float inv = SshInv;
        int el = t >> 6, ant = t & 63;
        out[a * 512 + t] = o1[el][ant] * inv;
        out[65536 + a * 512 + t] = o1[el][64 + ant] * inv;
        if (t < 64) {
            float sr = 0.f, si = 0.f;
#pragma unroll
            for (int u = 0; u < 8; ++u) {
                sr += o1[u][t];
                si += o1[u][64 + t];
            }
            sr *= inv;
            si *= inv;
            Q[a * 64 + t] = sr * sr + si * si;
        }
    }
}

// ---------------------------------------------------------------------------
// Kernel D: final aggregate from fp16 P (16.8 MB). One wave per j.
// ---------------------------------------------------------------------------
__global__ __launch_bounds__(256) void final_agg(const unsigned short* __restrict__ Pws,
                                                 const float* __restrict__ Qv,
                                                 float* __restrict__ out) {
    int bid = blockIdx.x, t = threadIdx.x, w = t >> 6, l = t & 63;
    __shared__ __attribute__((aligned(16))) float Qc[128][68];
    for (int i = t; i < 8192; i += 256) Qc[i >> 6][i & 63] = Qv[i];
    __syncthreads();
    int j = bid * 4 + w;
    int as = l >> 3, og = l & 7;
    float acc = 0.f;
#pragma unroll 4
    for (int ab = 0; ab < 16; ++ab) {
        int aa = ab * 8 + as;
        uint4 pv4 = *reinterpret_cast<const uint4*>(&Pws[(unsigned)(aa * 1024 + j) * 64 + og * 8]);
        float4 q0 = *reinterpret_cast<const float4*>(&Qc[aa][og * 8]);
        float4 q1 = *reinterpret_cast<const float4*>(&Qc[aa][og * 8 + 4]);
        const unsigned short* hp = (const unsigned short*)&pv4;
        acc += __half2float(__ushort_as_half(hp[0])) * q0.x;
        acc += __half2float(__ushort_as_half(hp[1])) * q0.y;
        acc += __half2float(__ushort_as_half(hp[2])) * q0.z;
        acc += __half2float(__ushort_as_half(hp[3])) * q0.w;
        acc += __half2float(__ushort_as_half(hp[4])) * q1.x;
        acc += __half2float(__ushort_as_half(hp[5])) * q1.y;
        acc += __half2float(__ushort_as_half(hp[6])) * q1.z;
        acc += __half2float(__ushort_as_half(hp[7])) * q1.w;
    }
    for (int m = 1; m < 64; m <<= 1) acc += __shfl_xor(acc, m, 64);
    if (l == 0) out[131072 + j] = acc;
}

extern "C" void kernel_launch(void* const* d_in, const int* in_sizes, int n_in,
                              void* d_out, int out_size, void* d_ws, size_t ws_size,
                              hipStream_t stream) {
    const float* plre = (const float*)d_in[0];
    const float* plim = (const float*)d_in[1];
    const float* pldre = (const float*)d_in[2];
    const float* pldim = (const float*)d_in[3];
    const float* pvre = (const float*)d_in[4];
    const float* pvim = (const float*)d_in[5];
    const float* W2a = (const float*)d_in[6];
    const float* b2a = (const float*)d_in[7];
    const float* W2b = (const float*)d_in[8];
    const float* b2b = (const float*)d_in[9];
    const float* W1a = (const float*)d_in[10];
    const float* b1a = (const float*)d_in[11];
    const float* W1b = (const float*)d_in[12];
    const float* b1b = (const float*)d_in[13];

    char* ws = (char*)d_ws;
    float* Sa = (float*)(ws);                               // 131072 B
    unsigned short* WpF = (unsigned short*)(ws + 131072);   // 65536 B
    unsigned short* W2bF = (unsigned short*)(ws + 196608);  // 32768 B
    float* Q = (float*)(ws + 229376);                       // 32768 B
    float* W1aT = (float*)(ws + 262144);                    // 212992 B
    float* W1bT = (float*)(ws + 475136);                    // 131072 B
    float* partial = (float*)(ws + 606208);                 // 8388608 B (32 chunks)
    unsigned short* Pws = (unsigned short*)(ws + 8994816);  // 16777216 B
    float* out = (float*)d_out;

    prep_kernel<<<168, 256, 0, stream>>>(pvre, pvim, W2a, b2a, W2b, W1a, W1b,
                                         Sa, WpF, W2bF, W1aT, W1bT);
    mlp2_kernel<<<1024, 256, 0, stream>>>(plre, plim, Sa, WpF, W2bF, partial, Pws);
    dlink_norm<<<128, 512, 0, stream>>>(pvre, pvim, pldre, pldim, partial, b2b,
                                        W1aT, b1a, W1bT, b1b, Q, out);
    final_agg<<<256, 256, 0, stream>>>(Pws, Q, out);
}

// Round 10
// 66.219 us; speedup vs baseline: 1.6987x; 1.1540x over previous
//
#include <hip/hip_runtime.h>
#include <hip/hip_bf16.h>
#include <hip/hip_fp16.h>

#define A_NUM 128
#define U_NUM 8
#define ANT 64
#define D2 64
#define H_DIM 256
#define NUE 1024
#define E_INT 131072

typedef __attribute__((ext_vector_type(8))) short bf16x8_t;
typedef __attribute__((ext_vector_type(4))) short bf16x4_t;
typedef __attribute__((ext_vector_type(4))) float f32x4_t;

// round-to-nearest-even f32 -> bf16
static __device__ inline unsigned short f2bf(float x) {
    unsigned int u = __float_as_uint(x);
    unsigned int r = (u + 0x7fffu + ((u >> 16) & 1u)) >> 16;
    return (unsigned short)r;
}
static __device__ inline unsigned int pack2(float a, float b) {
    return (unsigned int)f2bf(a) | ((unsigned int)f2bf(b) << 16);
}
static __device__ inline unsigned int packh2(float a, float b) {
    return (unsigned int)__half_as_ushort(__float2half(a)) |
           ((unsigned int)__half_as_ushort(__float2half(b)) << 16);
}
// relu + cvt to l2 B-frag (k = lk*4 + i matches rows r of l1T output)
static __device__ inline bf16x4_t relu_cvt4(f32x4_t v) {
    float t0 = v[0] > 0.f ? v[0] : 0.f;
    float t1 = v[1] > 0.f ? v[1] : 0.f;
    float t2 = v[2] > 0.f ? v[2] : 0.f;
    float t3 = v[3] > 0.f ? v[3] : 0.f;
    union { unsigned int u[2]; bf16x4_t s; } r;
    r.u[0] = pack2(t0, t1);
    r.u[1] = pack2(t2, t3);
    return r.s;
}

// ---------------------------------------------------------------------------
// Kernel A: prep. blocks 0..127: Sa[a,h]. blocks 128..135: fragment-order
// bf16 weight packs WpF (l1 A-frags) / W2F (l2 A-frags, K=16 layout).
// blocks 136..167: f32 transposes W1aT[256][208] (pad), W1bT[128][256].
//
// WpF flat = ((hh*8 + ht8)*4 + kc)*512 + l*8 + i
//   -> Wp[h][k], h = hh*128 + ht8*16 + (l&15), k = kc*32 + (l>>4)*8 + i,
//      Wp[h][k] = W2a[k<64 ? k : k+64][h]
// W2F flat = ((hh*8 + ht8)*4 + dt)*256 + l*4 + i
//   -> W2b[k][d], d = dt*16 + (l&15), k = hh*128 + ht8*16 + (l>>4)*4 + i
// ---------------------------------------------------------------------------
__global__ void prep_kernel(const float* __restrict__ pv_re, const float* __restrict__ pv_im,
                            const float* __restrict__ W2a, const float* __restrict__ b2a,
                            const float* __restrict__ W2b,
                            const float* __restrict__ W1a, const float* __restrict__ W1b,
                            float* __restrict__ Sa, unsigned short* __restrict__ WpF,
                            unsigned short* __restrict__ W2F,
                            float* __restrict__ W1aT, float* __restrict__ W1bT) {
    int bid = blockIdx.x, t = threadIdx.x;
    if (bid < A_NUM) {
        __shared__ float sre[ANT], sim[ANT];
        if (t < ANT) {
            float s = 0.f;
            for (int u = 0; u < U_NUM; ++u) s += pv_re[bid * 512 + u * 64 + t];
            sre[t] = s;
        } else if (t < 2 * ANT) {
            int ant = t - ANT;
            float s = 0.f;
            for (int u = 0; u < U_NUM; ++u) s += pv_im[bid * 512 + u * 64 + ant];
            sim[ant] = s;
        }
        __syncthreads();
        float a0 = 0.f, a1 = 0.f, a2 = 0.f, a3 = 0.f;
        for (int ant = 0; ant < ANT; ant += 2) {
            a0 += sre[ant] * W2a[(64 + ant) * H_DIM + t];
            a1 += sim[ant] * W2a[(192 + ant) * H_DIM + t];
            a2 += sre[ant + 1] * W2a[(64 + ant + 1) * H_DIM + t];
            a3 += sim[ant + 1] * W2a[(192 + ant + 1) * H_DIM + t];
        }
        Sa[bid * H_DIM + t] = b2a[t] + ((a0 + a2) + (a1 + a3));
    } else if (bid < 136) {
        int base = (bid - A_NUM) * 256 + t;
        for (int f = base; f < 32768 + 16384; f += 8 * 256) {
            if (f < 32768) {  // WpF (l1 A-frags, K=32 layout)
                int i = f & 7, lml = (f >> 3) & 15, lkl = (f >> 7) & 3;
                int kc = (f >> 9) & 3, ht8 = (f >> 11) & 7, hh = (f >> 14) & 1;
                int h = hh * 128 + ht8 * 16 + lml;
                int k = kc * 32 + lkl * 8 + i;
                int row = (k < 64) ? k : (k + 64);
                WpF[f] = f2bf(W2a[row * H_DIM + h]);
            } else {          // W2F (l2 A-frags, K=16 layout)
                int f2 = f - 32768;
                int i = f2 & 3, ll = (f2 >> 2) & 63;
                int dt = (f2 >> 8) & 3, ht8 = (f2 >> 10) & 7, hh = (f2 >> 13) & 1;
                int d = dt * 16 + (ll & 15);
                int k = hh * 128 + ht8 * 16 + (ll >> 4) * 4 + i;
                W2F[f2] = f2bf(W2b[k * D2 + d]);
            }
        }
    } else {
        for (int i = (bid - 136) * 256 + t; i < 53248 + 32768; i += 32 * 256) {
            if (i < 53248) {
                int k = i >> 8, h = i & 255;
                W1aT[h * 208 + k] = (k < 193) ? W1a[k * 256 + h] : 0.f;
            } else {
                int i2 = i - 53248;
                int k = i2 >> 7, c = i2 & 127;
                W1bT[c * 256 + k] = W1b[k * 128 + c];
            }
        }
    }
}

// ---------------------------------------------------------------------------
// Kernel B: big edge MLP, transpose-free. Grid 512 = 16 jt(64j) x 2 hh x 16 ac,
// exactly 2 blocks/CU. 512 thr / 8 waves = 2 jw(32j) x 4 hw(32h of hh-half).
// l1 swapped (D1T[h][j] = Wp x F^T): output feeds l2's 16x16x16 B-frag
// directly in registers (relu+cvt, no LDS round trip). l2 k-split by hw;
// hw-partials folded in-block via the dead F buffer. LDS 65KB -> 4 waves/SIMD.
// ---------------------------------------------------------------------------
__global__ __launch_bounds__(512) void mlp2_kernel(
        const float* __restrict__ plre, const float* __restrict__ plim,
        const float* __restrict__ Sa, const unsigned short* __restrict__ WpF,
        const unsigned short* __restrict__ W2F, float* __restrict__ partial,
        unsigned short* __restrict__ Pws) {
    __shared__ __attribute__((aligned(16))) unsigned short Wl[16384];   // 32KB
    __shared__ __attribute__((aligned(16))) unsigned short W2l[8192];   // 16KB
    __shared__ __attribute__((aligned(16))) unsigned short Fbuf[8704];  // [64 j][136 k] 17KB
    int bid = blockIdx.x;
    int ac = bid >> 5, hh = (bid >> 4) & 1, jtile = bid & 15;
    int j0 = jtile * 64, a0 = ac * 8;
    int t = threadIdx.x, l = t & 63, lm = l & 15, lk = l >> 4;
    int wv = t >> 6, jw = wv >> 2, hw = wv & 3;

    // ---- stage this hh-half's weights into LDS (once) ----
    {
        const uint4* sW = reinterpret_cast<const uint4*>(WpF + hh * 16384);
        const uint4* sW2 = reinterpret_cast<const uint4*>(W2F + hh * 8192);
        uint4* dW = reinterpret_cast<uint4*>(Wl);
        uint4* dW2 = reinterpret_cast<uint4*>(W2l);
        for (int q = t; q < 3072; q += 512) {
            if (q < 2048) dW[q] = sW[q];
            else dW2[q - 2048] = sW2[q - 2048];
        }
    }

    // ---- staging identity: thread t -> (row er, 16-col segment sg) ----
    int er = t >> 3, sg = t & 7;
    const float* sb = (sg < 4) ? plre : plim;
    int soff = (j0 + er) * 64 + (sg & 3) * 16;
    int fw = er * 136 + ((sg < 4) ? 0 : 64) + (sg & 3) * 16;

    f32x4_t acc2[4][2];  // [dt][jt], accumulated over (a, ht)
#pragma unroll
    for (int dt = 0; dt < 4; ++dt)
#pragma unroll
        for (int jt = 0; jt < 2; ++jt) acc2[dt][jt] = (f32x4_t){0.f, 0.f, 0.f, 0.f};

    float4 s0, s1, s2, s3;
    {   // stage a0 directly
        const float* p = sb + (size_t)a0 * 65536 + soff;
        s0 = *reinterpret_cast<const float4*>(p);
        s1 = *reinterpret_cast<const float4*>(p + 4);
        s2 = *reinterpret_cast<const float4*>(p + 8);
        s3 = *reinterpret_cast<const float4*>(p + 12);
        *reinterpret_cast<uint4*>(&Fbuf[fw]) =
            make_uint4(pack2(s0.x, s0.y), pack2(s0.z, s0.w),
                       pack2(s1.x, s1.y), pack2(s1.z, s1.w));
        *reinterpret_cast<uint4*>(&Fbuf[fw + 8]) =
            make_uint4(pack2(s2.x, s2.y), pack2(s2.z, s2.w),
                       pack2(s3.x, s3.y), pack2(s3.z, s3.w));
    }
    {   // prefetch a1
        const float* p = sb + (size_t)(a0 + 1) * 65536 + soff;
        s0 = *reinterpret_cast<const float4*>(p);
        s1 = *reinterpret_cast<const float4*>(p + 4);
        s2 = *reinterpret_cast<const float4*>(p + 8);
        s3 = *reinterpret_cast<const float4*>(p + 12);
    }
    __syncthreads();  // weights + F(a0) visible

    for (int ai = 0; ai < 8; ++ai) {
        int a = a0 + ai;
        // ---- P emit (hh==0): P[e][ant] = re^2 + im^2 (fp16) ----
        if (hh == 0) {
            uint4 rr = *reinterpret_cast<const uint4*>(Fbuf + er * 136 + sg * 8);
            uint4 ri = *reinterpret_cast<const uint4*>(Fbuf + er * 136 + 64 + sg * 8);
            const unsigned short* pr = (const unsigned short*)&rr;
            const unsigned short* pi = (const unsigned short*)&ri;
            unsigned int pk[4];
#pragma unroll
            for (int i = 0; i < 4; ++i) {
                float re0 = __uint_as_float(((unsigned int)pr[2 * i]) << 16);
                float im0 = __uint_as_float(((unsigned int)pi[2 * i]) << 16);
                float re1 = __uint_as_float(((unsigned int)pr[2 * i + 1]) << 16);
                float im1 = __uint_as_float(((unsigned int)pi[2 * i + 1]) << 16);
                pk[i] = packh2(re0 * re0 + im0 * im0, re1 * re1 + im1 * im1);
            }
            *reinterpret_cast<uint4*>(&Pws[(unsigned)(a * 1024 + j0 + er) * 64 + sg * 8]) =
                make_uint4(pk[0], pk[1], pk[2], pk[3]);
        }
        // ---- layer 1 (swapped): D1T[h][j], wave tile 32h x 32j ----
        f32x4_t acc1[2][2];  // [ht][jt]
#pragma unroll
        for (int ht = 0; ht < 2; ++ht) {
            f32x4_t sa = *reinterpret_cast<const f32x4_t*>(
                Sa + a * H_DIM + hh * 128 + hw * 32 + ht * 16 + lk * 4);
            acc1[ht][0] = sa;
            acc1[ht][1] = sa;
        }
#pragma unroll
        for (int kc = 0; kc < 4; ++kc) {
            bf16x8_t aw0 = *reinterpret_cast<const bf16x8_t*>(
                Wl + (((hw * 2 + 0) * 4 + kc) << 9) + l * 8);
            bf16x8_t aw1 = *reinterpret_cast<const bf16x8_t*>(
                Wl + (((hw * 2 + 1) * 4 + kc) << 9) + l * 8);
            bf16x8_t bf0 = *reinterpret_cast<const bf16x8_t*>(
                Fbuf + (jw * 32 + lm) * 136 + kc * 32 + lk * 8);
            bf16x8_t bf1 = *reinterpret_cast<const bf16x8_t*>(
                Fbuf + (jw * 32 + 16 + lm) * 136 + kc * 32 + lk * 8);
            acc1[0][0] = __builtin_amdgcn_mfma_f32_16x16x32_bf16(aw0, bf0, acc1[0][0], 0, 0, 0);
            acc1[0][1] = __builtin_amdgcn_mfma_f32_16x16x32_bf16(aw0, bf1, acc1[0][1], 0, 0, 0);
            acc1[1][0] = __builtin_amdgcn_mfma_f32_16x16x32_bf16(aw1, bf0, acc1[1][0], 0, 0, 0);
            acc1[1][1] = __builtin_amdgcn_mfma_f32_16x16x32_bf16(aw1, bf1, acc1[1][1], 0, 0, 0);
        }
        // ---- layer 2: relu+cvt in-register, 16x16x16 MFMA, K=16 per ht ----
#pragma unroll
        for (int ht = 0; ht < 2; ++ht) {
            bf16x4_t hl0 = relu_cvt4(acc1[ht][0]);
            bf16x4_t hl1 = relu_cvt4(acc1[ht][1]);
#pragma unroll
            for (int dt = 0; dt < 4; ++dt) {
                bf16x4_t w2 = *reinterpret_cast<const bf16x4_t*>(
                    W2l + (((hw * 2 + ht) * 4 + dt) << 8) + l * 4);
                acc2[dt][0] = __builtin_amdgcn_mfma_f32_16x16x16bf16_1k(w2, hl0, acc2[dt][0], 0, 0, 0);
                acc2[dt][1] = __builtin_amdgcn_mfma_f32_16x16x16bf16_1k(w2, hl1, acc2[dt][1], 0, 0, 0);
            }
        }
        // ---- restage F for a+1 (single buffer, 2 barriers) ----
        if (ai < 7) {
            __syncthreads();  // all F reads done
            *reinterpret_cast<uint4*>(&Fbuf[fw]) =
                make_uint4(pack2(s0.x, s0.y), pack2(s0.z, s0.w),
                           pack2(s1.x, s1.y), pack2(s1.z, s1.w));
            *reinterpret_cast<uint4*>(&Fbuf[fw + 8]) =
                make_uint4(pack2(s2.x, s2.y), pack2(s2.z, s2.w),
                           pack2(s3.x, s3.y), pack2(s3.z, s3.w));
            if (ai < 6) {
                const float* p = sb + (size_t)(a0 + ai + 2) * 65536 + soff;
                s0 = *reinterpret_cast<const float4*>(p);
                s1 = *reinterpret_cast<const float4*>(p + 4);
                s2 = *reinterpret_cast<const float4*>(p + 8);
                s3 = *reinterpret_cast<const float4*>(p + 12);
            }
            __syncthreads();  // F(a+1) ready
        }
    }

    // ---- fold hw-partials via dead F buffer ([64 j][68 d] f32 = 17408B) ----
    float* R = reinterpret_cast<float*>(Fbuf);
#define STORE_R()                                                              \
    do {                                                                       \
        _Pragma("unroll") for (int dt = 0; dt < 4; ++dt)                       \
            _Pragma("unroll") for (int jt = 0; jt < 2; ++jt)                   \
                *reinterpret_cast<f32x4_t*>(                                   \
                    &R[(jw * 32 + jt * 16 + lm) * 68 + dt * 16 + lk * 4]) =    \
                    acc2[dt][jt];                                              \
    } while (0)
#define ADD_R()                                                                \
    do {                                                                       \
        _Pragma("unroll") for (int dt = 0; dt < 4; ++dt)                       \
            _Pragma("unroll") for (int jt = 0; jt < 2; ++jt)                   \
                acc2[dt][jt] += *reinterpret_cast<const f32x4_t*>(             \
                    &R[(jw * 32 + jt * 16 + lm) * 68 + dt * 16 + lk * 4]);     \
    } while (0)
    __syncthreads();
    if (hw == 1) STORE_R();
    __syncthreads();
    if (hw == 0) ADD_R();
    __syncthreads();
    if (hw == 3) STORE_R();
    __syncthreads();
    if (hw == 2) ADD_R();
    __syncthreads();
    if (hw == 2) STORE_R();
    __syncthreads();
    if (hw == 0) {
        ADD_R();
#pragma unroll
        for (int dt = 0; dt < 4; ++dt)
#pragma unroll
            for (int jt = 0; jt < 2; ++jt)
                *reinterpret_cast<float4*>(
                    &partial[(size_t)(hh * 16 + ac) * 65536 +
                             (j0 + jw * 32 + jt * 16 + lm) * 64 + dt * 16 + lk * 4]) =
                    *reinterpret_cast<float4*>(&acc2[dt][jt]);
    }
#undef STORE_R
#undef ADD_R
}

// ---------------------------------------------------------------------------
// Kernel C: fused d-link MLP + per-AP normalization. One block per AP,
// 512 threads. Folds the 32-chunk partial reduction for its 8 ue rows.
// ---------------------------------------------------------------------------
__global__ __launch_bounds__(512) void dlink_norm(
        const float* __restrict__ pv_re, const float* __restrict__ pv_im,
        const float* __restrict__ pldre, const float* __restrict__ pldim,
        const float* __restrict__ partial, const float* __restrict__ b2b,
        const float* __restrict__ W1aT, const float* __restrict__ b1a,
        const float* __restrict__ W1bT, const float* __restrict__ b1b,
        float* __restrict__ Q, float* __restrict__ out) {
    int a = blockIdx.x, t = threadIdx.x, w = t >> 6, l = t & 63;
    __shared__ float pvr[512], pvi[512], pldr[512], pldi[512];
    __shared__ float nrm[8][8];
    __shared__ __attribute__((aligned(16))) float feat[8][212];
    __shared__ __attribute__((aligned(16))) float h1[8][260];
    __shared__ float red2[2][8][128];
    __shared__ __attribute__((aligned(16))) float o1[8][128];
    __shared__ float redn[8];
    __shared__ float SshInv;

    pvr[t] = pv_re[a * 512 + t];
    pvi[t] = pv_im[a * 512 + t];
    pldr[t] = pldre[a * 512 + t];
    pldi[t] = pldim[a * 512 + t];
    {
        float acc = 128.f * b2b[t & 63];
#pragma unroll
        for (int c = 0; c < 32; ++c) acc += partial[c * 65536 + a * 512 + t];
        feat[t >> 6][129 + (t & 63)] = acc;
    }
    if (t < 152) feat[t / 19][193 + t % 19] = 0.f;
    __syncthreads();
    feat[t >> 6][1 + (t & 63)] = pldr[t];
    feat[t >> 6][65 + (t & 63)] = pldi[t];
#pragma unroll
    for (int p = 0; p < 8; ++p) {
        int idx = w * 8 + p;
        int el = idx >> 3, u = idx & 7;
        float pr = pvr[u * 64 + l], pi = pvi[u * 64 + l];
        float qr = pldr[el * 64 + l], qi = pldi[el * 64 + l];
        float ir = pr * qr + pi * qi;
        float ii = pr * qi - pi * qr;
        for (int m = 1; m < 64; m <<= 1) {
            ir += __shfl_xor(ir, m, 64);
            ii += __shfl_xor(ii, m, 64);
        }
        if (l == 0) nrm[el][u] = ir * ir + ii * ii;
    }
    __syncthreads();
    if (t < 8) {
        float s = 0.f;
        for (int u = 0; u < 8; ++u)
            if (u != t) s += nrm[t][u];
        feat[t][0] = s;
    }
    __syncthreads();
    {
        int h = t >> 1, e0 = (t & 1) * 4;
        const float4* wrow = reinterpret_cast<const float4*>(W1aT + h * 208);
        const float4* f0p = reinterpret_cast<const float4*>(&feat[e0 + 0][0]);
        const float4* f1p = reinterpret_cast<const float4*>(&feat[e0 + 1][0]);
        const float4* f2p = reinterpret_cast<const float4*>(&feat[e0 + 2][0]);
        const float4* f3p = reinterpret_cast<const float4*>(&feat[e0 + 3][0]);
        float ac0 = 0.f, ac1 = 0.f, ac2 = 0.f, ac3 = 0.f;
#pragma unroll 4
        for (int kq = 0; kq < 52; ++kq) {
            float4 wv = wrow[kq];
            float4 f0 = f0p[kq], f1 = f1p[kq], f2 = f2p[kq], f3 = f3p[kq];
            ac0 = fmaf(wv.x, f0.x, ac0); ac0 = fmaf(wv.y, f0.y, ac0);
            ac0 = fmaf(wv.z, f0.z, ac0); ac0 = fmaf(wv.w, f0.w, ac0);
            ac1 = fmaf(wv.x, f1.x, ac1); ac1 = fmaf(wv.y, f1.y, ac1);
            ac1 = fmaf(wv.z, f1.z, ac1); ac1 = fmaf(wv.w, f1.w, ac1);
            ac2 = fmaf(wv.x, f2.x, ac2); ac2 = fmaf(wv.y, f2.y, ac2);
            ac2 = fmaf(wv.z, f2.z, ac2); ac2 = fmaf(wv.w, f2.w, ac2);
            ac3 = fmaf(wv.x, f3.x, ac3); ac3 = fmaf(wv.y, f3.y, ac3);
            ac3 = fmaf(wv.w, f3.w, ac3); ac3 = fmaf(wv.z, f3.z, ac3);
        }
        float bb = b1a[h];
        float s0 = bb + ac0, s1 = bb + ac1, s2 = bb + ac2, s3 = bb + ac3;
        h1[e0 + 0][h] = s0 > 0.f ? s0 : 0.f;
        h1[e0 + 1][h] = s1 > 0.f ? s1 : 0.f;
        h1[e0 + 2][h] = s2 > 0.f ? s2 : 0.f;
        h1[e0 + 3][h] = s3 > 0.f ? s3 : 0.f;
    }
    __syncthreads();
    {
        int e0 = (t & 1) * 4, c = (t >> 1) & 127, kh = t >> 8;
        const float4* wrow = reinterpret_cast<const float4*>(W1bT + c * 256 + kh * 128);
        const float4* g0 = reinterpret_cast<const float4*>(&h1[e0 + 0][kh * 128]);
        const float4* g1 = reinterpret_cast<const float4*>(&h1[e0 + 1][kh * 128]);
        const float4* g2 = reinterpret_cast<const float4*>(&h1[e0 + 2][kh * 128]);
        const float4* g3 = reinterpret_cast<const float4*>(&h1[e0 + 3][kh * 128]);
        float ac0 = 0.f, ac1 = 0.f, ac2 = 0.f, ac3 = 0.f;
#pragma unroll 4
        for (int kq = 0; kq < 32; ++kq) {
            float4 wv = wrow[kq];
            float4 f0 = g0[kq], f1 = g1[kq], f2 = g2[kq], f3 = g3[kq];
            ac0 = fmaf(wv.x, f0.x, ac0); ac0 = fmaf(wv.y, f0.y, ac0);
            ac0 = fmaf(wv.z, f0.z, ac0); ac0 = fmaf(wv.w, f0.w, ac0);
            ac1 = fmaf(wv.x, f1.x, ac1); ac1 = fmaf(wv.y, f1.y, ac1);
            ac1 = fmaf(wv.z, f1.z, ac1); ac1 = fmaf(wv.w, f1.w, ac1);
            ac2 = fmaf(wv.x, f2.x, ac2); ac2 = fmaf(wv.y, f2.y, ac2);
            ac2 = fmaf(wv.z, f2.z, ac2); ac2 = fmaf(wv.w, f2.w, ac2);
            ac3 = fmaf(wv.x, f3.x, ac3); ac3 = fmaf(wv.y, f3.y, ac3);
            ac3 = fmaf(wv.z, f3.z, ac3); ac3 = fmaf(wv.w, f3.w, ac3);
        }
        red2[kh][e0 + 0][c] = ac0;
        red2[kh][e0 + 1][c] = ac1;
        red2[kh][e0 + 2][c] = ac2;
        red2[kh][e0 + 3][c] = ac3;
    }
    __syncthreads();
    {
        int i0 = t, i1 = t + 512;
        o1[i0 >> 7][i0 & 127] = b1b[i0 & 127] + red2[0][i0 >> 7][i0 & 127] + red2[1][i0 >> 7][i0 & 127];
        o1[i1 >> 7][i1 & 127] = b1b[i1 & 127] + red2[0][i1 >> 7][i1 & 127] + red2[1][i1 >> 7][i1 & 127];
    }
    __syncthreads();
    {
        int el = t >> 6, ant = t & 63;
        float re = o1[el][ant], im = o1[el][64 + ant];
        float v = sqrtf(re * re + im * im);
        for (int m = 1; m < 64; m <<= 1) v += __shfl_xor(v, m, 64);
        if (l == 0) redn[w] = v;
    }
    __syncthreads();
    if (t == 0) {
        float S = redn[0] + redn[1] + redn[2] + redn[3] +
                  redn[4] + redn[5] + redn[6] + redn[7];
        SshInv = 1.f / S;
    }
    __syncthreads();
    {
        float inv = SshInv;
        int el = t >> 6, ant = t & 63;
        out[a * 512 + t] = o1[el][ant] * inv;
        out[65536 + a * 512 + t] = o1[el][64 + ant] * inv;
        if (t < 64) {
            float sr = 0.f, si = 0.f;
#pragma unroll
            for (int u = 0; u < 8; ++u) {
                sr += o1[u][t];
                si += o1[u][64 + t];
            }
            sr *= inv;
            si *= inv;
            Q[a * 64 + t] = sr * sr + si * si;
        }
    }
}

// ---------------------------------------------------------------------------
// Kernel D: final aggregate from fp16 P (16.8 MB). One wave per j.
// ---------------------------------------------------------------------------
__global__ __launch_bounds__(256) void final_agg(const unsigned short* __restrict__ Pws,
                                                 const float* __restrict__ Qv,
                                                 float* __restrict__ out) {
    int bid = blockIdx.x, t = threadIdx.x, w = t >> 6, l = t & 63;
    __shared__ __attribute__((aligned(16))) float Qc[128][68];
    for (int i = t; i < 8192; i += 256) Qc[i >> 6][i & 63] = Qv[i];
    __syncthreads();
    int j = bid * 4 + w;
    int as = l >> 3, og = l & 7;
    float acc = 0.f;
#pragma unroll 4
    for (int ab = 0; ab < 16; ++ab) {
        int aa = ab * 8 + as;
        uint4 pv4 = *reinterpret_cast<const uint4*>(&Pws[(unsigned)(aa * 1024 + j) * 64 + og * 8]);
        float4 q0 = *reinterpret_cast<const float4*>(&Qc[aa][og * 8]);
        float4 q1 = *reinterpret_cast<const float4*>(&Qc[aa][og * 8 + 4]);
        const unsigned short* hp = (const unsigned short*)&pv4;
        acc += __half2float(__ushort_as_half(hp[0])) * q0.x;
        acc += __half2float(__ushort_as_half(hp[1])) * q0.y;
        acc += __half2float(__ushort_as_half(hp[2])) * q0.z;
        acc += __half2float(__ushort_as_half(hp[3])) * q0.w;
        acc += __half2float(__ushort_as_half(hp[4])) * q1.x;
        acc += __half2float(__ushort_as_half(hp[5])) * q1.y;
        acc += __half2float(__ushort_as_half(hp[6])) * q1.z;
        acc += __half2float(__ushort_as_half(hp[7])) * q1.w;
    }
    for (int m = 1; m < 64; m <<= 1) acc += __shfl_xor(acc, m, 64);
    if (l == 0) out[131072 + j] = acc;
}

extern "C" void kernel_launch(void* const* d_in, const int* in_sizes, int n_in,
                              void* d_out, int out_size, void* d_ws, size_t ws_size,
                              hipStream_t stream) {
    const float* plre = (const float*)d_in[0];
    const float* plim = (const float*)d_in[1];
    const float* pldre = (const float*)d_in[2];
    const float* pldim = (const float*)d_in[3];
    const float* pvre = (const float*)d_in[4];
    const float* pvim = (const float*)d_in[5];
    const float* W2a = (const float*)d_in[6];
    const float* b2a = (const float*)d_in[7];
    const float* W2b = (const float*)d_in[8];
    const float* b2b = (const float*)d_in[9];
    const float* W1a = (const float*)d_in[10];
    const float* b1a = (const float*)d_in[11];
    const float* W1b = (const float*)d_in[12];
    const float* b1b = (const float*)d_in[13];

    char* ws = (char*)d_ws;
    float* Sa = (float*)(ws);                               // 131072 B
    unsigned short* WpF = (unsigned short*)(ws + 131072);   // 65536 B
    unsigned short* W2F = (unsigned short*)(ws + 196608);   // 32768 B
    float* Q = (float*)(ws + 229376);                       // 32768 B
    float* W1aT = (float*)(ws + 262144);                    // 212992 B
    float* W1bT = (float*)(ws + 475136);                    // 131072 B
    float* partial = (float*)(ws + 606208);                 // 8388608 B (32 chunks)
    unsigned short* Pws = (unsigned short*)(ws + 8994816);  // 16777216 B
    float* out = (float*)d_out;

    prep_kernel<<<168, 256, 0, stream>>>(pvre, pvim, W2a, b2a, W2b, W1a, W1b,
                                         Sa, WpF, W2F, W1aT, W1bT);
    mlp2_kernel<<<512, 512, 0, stream>>>(plre, plim, Sa, WpF, W2F, partial, Pws);
    dlink_norm<<<128, 512, 0, stream>>>(pvre, pvim, pldre, pldim, partial, b2b,
                                        W1aT, b1a, W1bT, b1b, Q, out);
    final_agg<<<256, 256, 0, stream>>>(Pws, Q, out);
}